// Round 13
// baseline (18756.506 us; speedup 1.0000x reference)
//
#include <hip/hip_runtime.h>
#include <math.h>

#define BB 128   // batch
#define TT 256   // time
#define DD 256   // input dims
#define UU 512   // units
#define RR 512   // ladder order

// ws layout (floats), row-major activations; x_j in X[j&1], m_j in M[j&1]:
//   X0 [128][512] @ 0
//   X1 [128][512] @ 65536
//   M0 [128][256] @ 131072
//   M1 [128][256] @ 163840
//   HZ [128][512] @ 196608   zeros (h_{-1})
#define OFF_X0 0
#define OFF_X1 65536
#define OFF_M0 131072
#define OFF_M1 163840
#define OFF_HZ 196608
#define WS_FLT 262144
#define WS_NEED_BYTES (WS_FLT * 4)   // 1,048,576 B (round-5 sentinel proved >= 1,310,720 available)

__global__ __launch_bounds__(256) void zero_kernel(float* __restrict__ p, int n)
{
    int i = blockIdx.x * 256 + threadIdx.x;
    if (i < n) p[i] = 0.0f;
}

// combo(t): 192 blocks x 256 threads. Launched for t = -1..255.
//  bid < 128 (h-part, t>=0): tile 2 rows x 256 cols, thread = 1 row x 2 cols.
//     h_t = tanhf(((aH+aX)+aF)+by)   [float2 weight loads]
//  bid >= 128 (x-part, t<=254): 64 blocks, tile 2 rows x 512 cols (FULL row),
//     thread = 1 row x 4 cols [float4 weight loads]:
//       x_{t+1} = aA + aB  -> global + LDS;  __syncthreads;
//       m_{t+1} = x_{t+1} @ CT for the same 2 rows (thread = 1 row x 2 cols, float2).
// Bitwise contract (= np ref, proven r7/r8): each dot = ascending-k
// single-accumulator fmaf chain from 0.0f; u = inp+m (one add); f = wfm*m
// (one mul); x = aA+aB (one add); z = ((aH+aX)+aF)+by. Vector weight loads
// and the LDS x-copy do not alter any chain's op sequence.
__global__ __launch_bounds__(256) void combo_kernel(
    const float* __restrict__ inputs, const float* __restrict__ wfm,
    const float* __restrict__ by,     const float* __restrict__ WyhT,
    const float* __restrict__ WyxT,   const float* __restrict__ WyfT,
    const float* __restrict__ AT,     const float* __restrict__ BT,
    const float* __restrict__ CT,
    const float* __restrict__ xin,    // x_t
    const float* __restrict__ min_,   // m_t
    const float* __restrict__ hz,     // zeros (h_{-1})
    float* __restrict__ xout,         // x_{t+1}
    float* __restrict__ mout,         // m_{t+1}
    float* __restrict__ out, int t)
{
    const int tid  = threadIdx.x;
    const int bid  = blockIdx.x;
    const int lane = tid & 63;
    const int wv   = tid >> 6;

    if (bid < 128) {
        // ================= h-part =================
        if (t < 0) return;
        const int cg  = bid & 1;
        const int rg  = bid >> 1;
        const int row = rg * 2 + (wv & 1);
        const int c   = cg * 256 + (wv >> 1) * 128 + lane * 2;

        const float* hr = (t == 0) ? (hz + row * UU)
                                   : (out + (row * TT + (t - 1)) * UU);
        const float* xr = xin + row * RR;
        float ah0 = 0.0f, ah1 = 0.0f, ax0 = 0.0f, ax1 = 0.0f;
        #pragma unroll 16
        for (int k = 0; k < UU; ++k) {
            float2 wh = *reinterpret_cast<const float2*>(&WyhT[k * UU + c]);
            float2 wx = *reinterpret_cast<const float2*>(&WyxT[k * UU + c]);
            float hv = hr[k];
            float xv = xr[k];
            ah0 = fmaf(hv, wh.x, ah0);
            ah1 = fmaf(hv, wh.y, ah1);
            ax0 = fmaf(xv, wx.x, ax0);
            ax1 = fmaf(xv, wx.y, ax1);
        }
        const float* mr = min_ + row * DD;
        float af0 = 0.0f, af1 = 0.0f;
        #pragma unroll 16
        for (int d = 0; d < DD; ++d) {
            float2 wf = *reinterpret_cast<const float2*>(&WyfT[d * UU + c]);
            float f = wfm[d] * mr[d];            // f = wfm*m_t (one mul, shared by cols)
            af0 = fmaf(f, wf.x, af0);
            af1 = fmaf(f, wf.y, af1);
        }
        float2 byv = *reinterpret_cast<const float2*>(&by[c]);
        float z0 = ((ah0 + ax0) + af0) + byv.x;
        float z1 = ((ah1 + ax1) + af1) + byv.y;
        float* op = out + (row * TT + t) * UU + c;
        op[0] = tanhf(z0);
        op[1] = tanhf(z1);
    } else {
        // ================= x-part (+ fused m) =================
        if (t > TT - 2) return;
        __shared__ float xl[2 * RR];             // this block's 2 rows of x_{t+1}
        const int xb  = bid - 128;               // 0..63
        const int rsel = wv & 1;
        const int row = xb * 2 + rsel;
        const int cq  = (wv >> 1) * 256 + lane * 4;   // 4-col quad

        const float* xr = xin + row * RR;
        float4 a = make_float4(0.f, 0.f, 0.f, 0.f);
        #pragma unroll 16
        for (int k = 0; k < RR; ++k) {
            float4 wA = *reinterpret_cast<const float4*>(&AT[k * RR + cq]);
            float xv = xr[k];
            a.x = fmaf(xv, wA.x, a.x);
            a.y = fmaf(xv, wA.y, a.y);
            a.z = fmaf(xv, wA.z, a.z);
            a.w = fmaf(xv, wA.w, a.w);
        }
        const float* ir = inputs + (row * TT + (t + 1)) * DD;
        const float* mr = min_ + row * DD;
        float4 b = make_float4(0.f, 0.f, 0.f, 0.f);
        #pragma unroll 16
        for (int d = 0; d < DD; ++d) {
            float4 wB = *reinterpret_cast<const float4*>(&BT[d * RR + cq]);
            float u = ir[d] + mr[d];             // u = inp_{t+1}+m_t (one add, shared)
            b.x = fmaf(u, wB.x, b.x);
            b.y = fmaf(u, wB.y, b.y);
            b.z = fmaf(u, wB.z, b.z);
            b.w = fmaf(u, wB.w, b.w);
        }
        float4 xv4;
        xv4.x = a.x + b.x;                       // dot + dot, one add each
        xv4.y = a.y + b.y;
        xv4.z = a.z + b.z;
        xv4.w = a.w + b.w;
        *reinterpret_cast<float4*>(&xout[row * RR + cq]) = xv4;
        *reinterpret_cast<float4*>(&xl[rsel * RR + cq])  = xv4;
        __syncthreads();

        // ---- m_{t+1} = x_{t+1} @ CT for these 2 rows ----
        const int   mrow = wv & 1;
        const int   mc   = (wv >> 1) * 128 + lane * 2;   // 0..254
        const float* xlr = xl + mrow * RR;
        float m0 = 0.0f, m1 = 0.0f;
        #pragma unroll 16
        for (int k = 0; k < RR; ++k) {
            float2 wC = *reinterpret_cast<const float2*>(&CT[k * DD + mc]);
            float xv = xlr[k];
            m0 = fmaf(xv, wC.x, m0);
            m1 = fmaf(xv, wC.y, m1);
        }
        float* mp = mout + (xb * 2 + mrow) * DD + mc;
        mp[0] = m0;
        mp[1] = m1;
    }
}

__global__ __launch_bounds__(64) void sentinel_kernel(float* __restrict__ out, float v)
{
    if (threadIdx.x == 0 && blockIdx.x == 0) out[0] = v;
}

extern "C" void kernel_launch(void* const* d_in, const int* in_sizes, int n_in,
                              void* d_out, int out_size, void* d_ws, size_t ws_size,
                              hipStream_t stream)
{
    const float* inputs = (const float*)d_in[0];
    const float* wfm    = (const float*)d_in[1];
    const float* WyhT   = (const float*)d_in[2];
    const float* WyxT   = (const float*)d_in[3];
    const float* WyfT   = (const float*)d_in[4];
    const float* by     = (const float*)d_in[5];
    const float* AT     = (const float*)d_in[6];
    const float* BT     = (const float*)d_in[7];
    const float* CT     = (const float*)d_in[8];
    float* out = (float*)d_out;
    float* ws  = (float*)d_ws;

    // Environment sentinels (absmax reveals code if triggered).
    double code = 0.0;
    static const int exp_sizes[9] = {8388608, 256, 262144, 262144, 131072,
                                     512, 262144, 131072, 131072};
    if (n_in != 9) {
        code = 3.0e6 + n_in;
    } else {
        for (int i = 0; i < 9; ++i)
            if (in_sizes[i] != exp_sizes[i]) { code = 2.0e6 + i * 1.0e4; break; }
    }
    if (code == 0.0 && out_size != BB * TT * UU)
        code = 4.0e6 + (double)(out_size / 10000);
    if (code == 0.0 && ws_size < (size_t)WS_NEED_BYTES)
        code = 1.0e6 + (double)(ws_size / 1024);
    if (code != 0.0) {
        sentinel_kernel<<<1, 64, 0, stream>>>(out, (float)code);
        return;
    }

    float* X0 = ws + OFF_X0;
    float* X1 = ws + OFF_X1;
    float* M0 = ws + OFF_M0;
    float* M1 = ws + OFF_M1;
    float* HZ = ws + OFF_HZ;

    // Zero all state: x_{-1} (X1), m_{-1} (M1), h_{-1} (HZ) must be exact 0.
    zero_kernel<<<(WS_FLT + 255) / 256, 256, 0, stream>>>(ws, WS_FLT);

    // combo(t), t=-1..255:
    //   t=-1: x-part only -> x_0 (X0) + m_0 (M0)
    //   t=0..254: h_t ; x_{t+1} + m_{t+1}
    //   t=255: h_255 only
    for (int t = -1; t < TT; ++t) {
        const float* xc = ((t & 1) == 0) ? X0 : X1;         // x_t   (t=-1 -> X1 zeros)
        float*       xn = (((t + 1) & 1) == 0) ? X0 : X1;   // x_{t+1}
        const float* mc = ((t & 1) == 0) ? M0 : M1;         // m_t   (t=-1 -> M1 zeros)
        float*       mn = (((t + 1) & 1) == 0) ? M0 : M1;   // m_{t+1}
        combo_kernel<<<192, 256, 0, stream>>>(inputs, wfm, by, WyhT, WyxT, WyfT,
                                              AT, BT, CT, xc, mc, HZ, xn, mn, out, t);
    }
}